// Round 8
// baseline (236.025 us; speedup 1.0000x reference)
//
#include <hip/hip_runtime.h>
#include <string.h>

// GraphSAGE 2-layer + linear head, N=50000, E=600000, C=128 everywhere.
// R7: (a) fp8(e4m3) gather tables for BOTH aggregates (rows 128B, 8 edges
//     per wave-instr, fp32 accum; HW cvt_pk builtins w/ bit-trick fallback)
//     — agg is bytes-bound (2x ILP gave 2x, 3x more in flight gave 0).
//     (b) revert col-split gemm (measured +4: A-traffic doubled, occupancy
//     wasn't the limiter). (c) fold radix_hist into prep; fold scan_add into
//     scatter/bucket via inline 32-entry sums-prefix. 13 -> 10 launches.

typedef _Float16 f16;
typedef unsigned int u32;
typedef __attribute__((ext_vector_type(4))) _Float16 f16x4;
typedef __attribute__((ext_vector_type(8))) _Float16 f16x8;
typedef __attribute__((ext_vector_type(4))) float f32x4;
typedef __attribute__((ext_vector_type(2))) float f32x2;

#define RNB 128   // radix blocks (256 bins x 128 = 32768 scan entries)

// ---------- fp8 e4m3 helpers (HW path + portable fallback) ----------
#if __has_builtin(__builtin_amdgcn_cvt_pk_f32_fp8)
#define DEC_SCALE 1.0f
__device__ inline void dec4(u32 v, float* o) {
  f32x2 a = __builtin_amdgcn_cvt_pk_f32_fp8((int)v, false);
  f32x2 b = __builtin_amdgcn_cvt_pk_f32_fp8((int)v, true);
  o[0] = a.x; o[1] = a.y; o[2] = b.x; o[3] = b.y;
}
#else
#define DEC_SCALE 256.0f   // bit-trick produces value * 2^-8; folded into mean
__device__ inline void dec4(u32 v, float* o) {
#pragma unroll
  for (int i = 0; i < 4; ++i) {
    u32 byte = (v >> (8 * i)) & 0xffu;
    union { unsigned short u; _Float16 h; } cv;
    cv.u = (unsigned short)(((byte & 0x80u) << 8) | ((byte & 0x7fu) << 7));
    o[i] = (float)cv.h;
  }
}
#endif

#if __has_builtin(__builtin_amdgcn_cvt_pk_fp8_f32)
__device__ inline u32 enc4(float a, float b, float c, float d) {
  u32 v = 0;
  v = (u32)__builtin_amdgcn_cvt_pk_fp8_f32(a, b, (int)v, false);
  v = (u32)__builtin_amdgcn_cvt_pk_fp8_f32(c, d, (int)v, true);
  return v;
}
#else
__device__ inline u32 enc1(float x) {
  union { unsigned short u; _Float16 h; } cv;
  cv.h = (_Float16)x;
  u32 hb = cv.u;
  u32 s = (hb >> 8) & 0x80u;
  int e = (int)((hb >> 10) & 0x1f);
  u32 m = hb & 0x3ffu;
  if (e == 0) return s;                    // below e4m3 denorm range
  int e8 = e - 8;
  if (e8 <= 0) {                           // e4m3 denormal
    int sh = 7 + (1 - e8);
    u32 full = 0x400u | m;
    u32 m3 = (sh < 31) ? (full >> sh) : 0;
    u32 r = (sh - 1 < 31) ? ((full >> (sh - 1)) & 1u) : 0;
    m3 += r; if (m3 > 7) m3 = 7;
    return s | m3;
  }
  u32 m3 = m >> 7;
  m3 += (m >> 6) & 1u;
  if (m3 == 8) { m3 = 0; e8++; }
  if (e8 >= 16 || (e8 == 15 && m3 == 7)) return s | 0x7Eu;   // clamp to 448
  return s | ((u32)e8 << 3) | m3;
}
__device__ inline u32 enc4(float a, float b, float c, float d) {
  return enc1(a) | (enc1(b) << 8) | (enc1(c) << 16) | (enc1(d) << 24);
}
#endif

// ---- prep: [0,cb) convert x -> f16 + fp8 | [cb,cb+wb) weights | rest: hist
// weights k-chunked transposed, 3 tables contiguous (32768 f16 each):
// wt[w][(chunk*128 + n)*8 + j] = W_w[k=chunk*8+j][n], W = [WA;WB] stacked.
__global__ void prep_kernel(const float* __restrict__ x, f16* __restrict__ xh,
                            u32* __restrict__ xh8, int n4,
                            const int* __restrict__ ei, int* __restrict__ ghist, int E,
                            const float* __restrict__ W1l, const float* __restrict__ W1r,
                            const float* __restrict__ W2l, const float* __restrict__ W2r,
                            const float* __restrict__ Wlin, f16* __restrict__ wt,
                            int cb, int wb) {
  int b = blockIdx.x;
  if (b < cb) {
    int i = b * 256 + threadIdx.x;
    if (i < n4) {
      const float4 v = ((const float4*)x)[i];
      f16x4 h = { (f16)v.x, (f16)v.y, (f16)v.z, (f16)v.w };
      ((f16x4*)xh)[i] = h;
      xh8[i] = enc4(v.x, v.y, v.z, v.w);
    }
  } else if (b < cb + wb) {
    int tid = (b - cb) * 256 + threadIdx.x;   // 0 .. 3*32768
    int w = tid >> 15, idx = tid & 32767;
    int j = idx & 7, n = (idx >> 3) & 127, chunk = idx >> 10;
    int k = chunk * 8 + j;
    float v;
    if (w == 0) v = (k < 128) ? W1l[k * 128 + n] : W1r[(k - 128) * 128 + n];
    else if (w == 1) v = (k < 128) ? W2l[k * 128 + n] : W2r[(k - 128) * 128 + n];
    else v = Wlin[k * 128 + n];
    wt[tid] = (f16)v;
  } else {
    __shared__ int h[256];
    int tid = threadIdx.x, rb = b - cb - wb;   // 0..RNB-1
    h[tid] = 0;
    __syncthreads();
    int per = (E + RNB - 1) / RNB;
    int s = rb * per, e = s + per; if (e > E) e = E;
    for (int i = s + tid; i < e; i += 256) atomicAdd(&h[ei[E + i] >> 8], 1);
    __syncthreads();
    ghist[tid * RNB + rb] = h[tid];
  }
}

// exclusive scan, 1024-elem chunks per block (Hillis-Steele, ping-pong LDS)
__global__ void scan_block_kernel(const int* __restrict__ in, int* __restrict__ out,
                                  int* __restrict__ sums, int n) {
  __shared__ int s[2][1024];
  int t = threadIdx.x;
  int gid = blockIdx.x * 1024 + t;
  int v = (gid < n) ? in[gid] : 0;
  int cur = 0;
  s[0][t] = v;
  __syncthreads();
  for (int ofs = 1; ofs < 1024; ofs <<= 1) {
    int nv = s[cur][t] + ((t >= ofs) ? s[cur][t - ofs] : 0);
    s[cur ^ 1][t] = nv;
    cur ^= 1;
    __syncthreads();
  }
  if (gid < n) out[gid] = s[cur][t] - v;      // exclusive within block
  if (t == 1023) sums[blockIdx.x] = s[cur][1023];
}

// inline exclusive prefix of the 32 chunk sums into LDS pf[32]
__device__ inline void sums_prefix(const int* sums, int* pf) {
  int t = threadIdx.x;
  if (t < 32) {
    int v = sums[t];
    int incl = v;
#pragma unroll
    for (int ofs = 1; ofs < 32; ofs <<= 1) {
      int u = __shfl_up(incl, ofs);
      if (t >= ofs) incl += u;
    }
    pf[t] = incl - v;
  }
}

// deterministic scatter into per-(block,bin) ranges; LDS cursors only.
// sg = within-chunk exclusive scan; chunk prefix added inline (chunk = bin>>3).
__global__ void radix_scatter(const int* __restrict__ ei, const int* __restrict__ sg,
                              const int* __restrict__ sums, int2* __restrict__ tmp, int E) {
  __shared__ int cur[256];
  __shared__ int pf[32];
  int tid = threadIdx.x, b = blockIdx.x;
  sums_prefix(sums, pf);
  __syncthreads();
  cur[tid] = sg[tid * RNB + b] + pf[tid >> 3];
  __syncthreads();
  int per = (E + RNB - 1) / RNB;
  int s = b * per, e = s + per; if (e > E) e = E;
  for (int i = s + tid; i < e; i += 256) {
    int d = ei[E + i], sr = ei[i];
    int pos = atomicAdd(&cur[d >> 8], 1);     // LDS atomic
    tmp[pos] = make_int2(d, sr);
  }
}

// one block per high-byte bucket: LDS low-byte hist + scan -> off[] + srcs.
__global__ void radix_bucket(const int2* __restrict__ tmp, const int* __restrict__ sg,
                             const int* __restrict__ sums, int* __restrict__ srcs,
                             int* __restrict__ off, int N, int E, int HB) {
  __shared__ int h[256], sc[256], cur[256];
  __shared__ int pf[32];
  int tid = threadIdx.x, hb = blockIdx.x;
  sums_prefix(sums, pf);
  __syncthreads();
  int start = sg[hb * RNB] + pf[hb >> 3];
  int end = (hb + 1 < HB) ? (sg[(hb + 1) * RNB] + pf[(hb + 1) >> 3]) : E;
  h[tid] = 0;
  __syncthreads();
  for (int i = start + tid; i < end; i += 256) atomicAdd(&h[tmp[i].x & 255], 1);
  __syncthreads();
  sc[tid] = h[tid];
  __syncthreads();
  for (int o = 1; o < 256; o <<= 1) {
    int u = (tid >= o) ? sc[tid - o] : 0;
    __syncthreads();
    sc[tid] += u;
    __syncthreads();
  }
  int excl = sc[tid] - h[tid];
  int v = (hb << 8) + tid;
  if (v < N) off[v] = start + excl;
  if (hb == 0 && tid == 0) off[N] = E;
  cur[tid] = start + excl;
  __syncthreads();
  for (int i = start + tid; i < end; i += 256) {
    int2 p = tmp[i];
    int pos = atomicAdd(&cur[p.x & 255], 1);  // LDS atomic
    srcs[pos] = p.y;
  }
}

// fp8 aggregate: wave = 2 nodes; lane = slot(sub=lane>>3: 8 edges) x c8(lane&7).
// Each lane loads 16B (16 fp8 ch) of its edge's row => 8 edges (1KB logical
// 128B-rows) per instr. Prefetch 3 rounds (24 edges/node), single drain,
// fp32 accum, cross-slot shfl reduce, f16 mean out.
#define AGG_R8 3
__global__ void aggregate8_kernel(const uint4* __restrict__ feat8, const int* __restrict__ off,
                                  const int* __restrict__ srcs, f16* __restrict__ meanf, int n) {
  int pair = (int)((blockIdx.x * blockDim.x + threadIdx.x) >> 6);
  int w0 = pair * 2;
  if (w0 >= n) return;
  int w1 = w0 + 1;
  int lane = threadIdx.x & 63;
  int sub = lane >> 3, c8 = lane & 7;
  int beg0 = off[w0], end0 = off[w0 + 1];
  int beg1 = end0;                              // CSR contiguity
  int end1 = (w1 < n) ? off[w1 + 1] : end0;
  int deg0 = end0 - beg0, deg1 = end1 - beg1;

  int s0[AGG_R8], s1[AGG_R8];
  bool v0[AGG_R8], v1[AGG_R8];
#pragma unroll
  for (int k = 0; k < AGG_R8; ++k) {
    int p = 8 * k + sub;
    v0[k] = p < deg0;  s0[k] = v0[k] ? srcs[beg0 + p] : 0;
    v1[k] = p < deg1;  s1[k] = v1[k] ? srcs[beg1 + p] : 0;
  }
  uint4 g0[AGG_R8], g1[AGG_R8];
#pragma unroll
  for (int k = 0; k < AGG_R8; ++k) {
    if (v0[k]) g0[k] = feat8[s0[k] * 8 + c8];
    if (v1[k]) g1[k] = feat8[s1[k] * 8 + c8];
  }
  float acc0[16] = {}, acc1[16] = {};
#pragma unroll
  for (int k = 0; k < AGG_R8; ++k) {
    float d[16];
    if (v0[k]) {
      dec4(g0[k].x, d); dec4(g0[k].y, d + 4); dec4(g0[k].z, d + 8); dec4(g0[k].w, d + 12);
#pragma unroll
      for (int j = 0; j < 16; ++j) acc0[j] += d[j];
    }
    if (v1[k]) {
      dec4(g1[k].x, d); dec4(g1[k].y, d + 4); dec4(g1[k].z, d + 8); dec4(g1[k].w, d + 12);
#pragma unroll
      for (int j = 0; j < 16; ++j) acc1[j] += d[j];
    }
  }
  for (int e = beg0 + 8 * AGG_R8; e < end0; e += 8) {   // rare deg>24 tail
    if (sub < end0 - e) {
      uint4 g = feat8[srcs[e + sub] * 8 + c8];
      float d[16];
      dec4(g.x, d); dec4(g.y, d + 4); dec4(g.z, d + 8); dec4(g.w, d + 12);
#pragma unroll
      for (int j = 0; j < 16; ++j) acc0[j] += d[j];
    }
  }
  for (int e = beg1 + 8 * AGG_R8; e < end1; e += 8) {
    if (sub < end1 - e) {
      uint4 g = feat8[srcs[e + sub] * 8 + c8];
      float d[16];
      dec4(g.x, d); dec4(g.y, d + 4); dec4(g.z, d + 8); dec4(g.w, d + 12);
#pragma unroll
      for (int j = 0; j < 16; ++j) acc1[j] += d[j];
    }
  }
#pragma unroll
  for (int j = 0; j < 16; ++j) {
    acc0[j] += __shfl_xor(acc0[j], 8);
    acc0[j] += __shfl_xor(acc0[j], 16);
    acc0[j] += __shfl_xor(acc0[j], 32);
    acc1[j] += __shfl_xor(acc1[j], 8);
    acc1[j] += __shfl_xor(acc1[j], 16);
    acc1[j] += __shfl_xor(acc1[j], 32);
  }
  if (sub == 0) {
    float inv = DEC_SCALE / fmaxf((float)deg0, 1.0f);
    f16x8 oa, ob;
#pragma unroll
    for (int j = 0; j < 8; ++j) { oa[j] = (f16)(acc0[j] * inv); ob[j] = (f16)(acc0[j + 8] * inv); }
    *(f16x8*)(meanf + (size_t)w0 * 128 + c8 * 16) = oa;
    *(f16x8*)(meanf + (size_t)w0 * 128 + c8 * 16 + 8) = ob;
  } else if (sub == 1 && w1 < n) {
    float inv = DEC_SCALE / fmaxf((float)deg1, 1.0f);
    f16x8 oa, ob;
#pragma unroll
    for (int j = 0; j < 8; ++j) { oa[j] = (f16)(acc1[j] * inv); ob[j] = (f16)(acc1[j + 8] * inv); }
    *(f16x8*)(meanf + (size_t)w1 * 128 + c8 * 16) = oa;
    *(f16x8*)(meanf + (size_t)w1 * 128 + c8 * 16 + 8) = ob;
  }
}

// x1h (f16) -> x1h8 (fp8), 8 elems/thread
__global__ void conv8_kernel(const f16* __restrict__ in, u32* __restrict__ out, int n8) {
  int i = blockIdx.x * blockDim.x + threadIdx.x;
  if (i < n8) {
    f16x8 v = ((const f16x8*)in)[i];
    uint2 o;
    o.x = enc4((float)v[0], (float)v[1], (float)v[2], (float)v[3]);
    o.y = enc4((float)v[4], (float)v[5], (float)v[6], (float)v[7]);
    ((uint2*)out)[i] = o;
  }
}

// GEMM v2 (R3): Y[M,128] = act([U|V][M,256] @ W + bias); Wt k-chunked in LDS.
// block = 256 = 4 waves; wave computes 32 rows x 128 cols (128 rows/block).
template <bool RELU, bool OUT16>
__global__ __launch_bounds__(256, 2) void gemm_kernel(
    const f16* __restrict__ U, const f16* __restrict__ V, const f16* __restrict__ Wt,
    const float* __restrict__ bias, void* __restrict__ outp, int M) {
  __shared__ f16 ldsb[32768];   // 64 KB
  int tid = threadIdx.x;
  int wave = tid >> 6, lane = tid & 63;
  int quad = lane >> 4, n15 = lane & 15;
  int m0 = blockIdx.x * 128 + wave * 32;
  int kq = quad * 8;

  f16x8 a[2][8];
#pragma unroll
  for (int r = 0; r < 2; ++r) {
    int row = m0 + r * 16 + n15;
    int rowc = row < M ? row : M - 1;   // clamp tail loads (stores guarded)
    const f16* bu = U + (size_t)rowc * 128 + kq;
    const f16* bv = V + (size_t)rowc * 128 + kq;
#pragma unroll
    for (int kk = 0; kk < 4; ++kk) a[r][kk] = *(const f16x8*)(bu + kk * 32);
#pragma unroll
    for (int kk = 4; kk < 8; ++kk) a[r][kk] = *(const f16x8*)(bv + (kk - 4) * 32);
  }

#pragma unroll
  for (int it = 0; it < 16; ++it) {
    int idx = it * 256 + tid;
    ((f16x8*)ldsb)[idx] = ((const f16x8*)Wt)[idx];
  }
  __syncthreads();

  f32x4 acc[2][8] = {};
#pragma unroll
  for (int kk = 0; kk < 8; ++kk) {
#pragma unroll
    for (int t = 0; t < 8; ++t) {
      f16x8 b = ((const f16x8*)ldsb)[(kk * 4 + quad) * 128 + t * 16 + n15];
#pragma unroll
      for (int r = 0; r < 2; ++r)
        acc[r][t] = __builtin_amdgcn_mfma_f32_16x16x32_f16(a[r][kk], b, acc[r][t], 0, 0, 0);
    }
  }

  int rbase0 = m0 + quad * 4;
#pragma unroll
  for (int t = 0; t < 8; ++t) {
    float bv = bias[t * 16 + n15];
#pragma unroll
    for (int r = 0; r < 2; ++r) {
#pragma unroll
      for (int i = 0; i < 4; ++i) {
        int row = rbase0 + r * 16 + i;
        if (row < M) {
          float v = acc[r][t][i] + bv;
          if (RELU) v = fmaxf(v, 0.f);
          size_t idx = (size_t)row * 128 + t * 16 + n15;
          if (OUT16) ((f16*)outp)[idx] = (f16)v;
          else       ((float*)outp)[idx] = v;
        }
      }
    }
  }
}

extern "C" void kernel_launch(void* const* d_in, const int* in_sizes, int n_in,
                              void* d_out, int out_size, void* d_ws, size_t ws_size,
                              hipStream_t stream) {
  (void)n_in; (void)out_size; (void)ws_size;
  const float* x    = (const float*)d_in[0];
  const int*   ei   = (const int*)d_in[1];
  const float* W1l  = (const float*)d_in[2];
  const float* b1l  = (const float*)d_in[3];
  const float* W1r  = (const float*)d_in[4];
  const float* W2l  = (const float*)d_in[5];
  const float* b2l  = (const float*)d_in[6];
  const float* W2r  = (const float*)d_in[7];
  const float* Wlin = (const float*)d_in[8];
  const float* blin = (const float*)d_in[9];
  const int N = in_sizes[0] / 128;
  const int E = in_sizes[1] / 2;

  char* ws = (char*)d_ws;
  size_t o = 0;
  auto alloc = [&](size_t bytes) {
    char* p = ws + o;
    o = (o + bytes + 255) & ~(size_t)255;
    return p;
  };
  f16*  xh   = (f16*)alloc((size_t)N * 128 * 2);
  f16*  x1h  = (f16*)alloc((size_t)N * 128 * 2);
  f16*  x2h  = (f16*)alloc((size_t)N * 128 * 2);
  f16*  mh   = (f16*)alloc((size_t)N * 128 * 2);
  u32*  xh8  = (u32*)alloc((size_t)N * 128);
  u32*  x1h8 = (u32*)alloc((size_t)N * 128);
  f16*  wt   = (f16*)alloc((size_t)3 * 32768 * 2);   // wt1|wt2|wt3 contiguous
  int*  off  = (int*)alloc(((size_t)N + 1) * 4);
  int*  srcs = (int*)alloc((size_t)E * 4);
  int2* tmp  = (int2*)alloc((size_t)E * 8);
  int*  ghist= (int*)alloc(256 * RNB * 4);
  int*  sg   = (int*)alloc(256 * RNB * 4);
  int*  sums = (int*)alloc(64 * 4);
  f16* wt1 = wt, *wt2 = wt + 32768, *wt3 = wt + 65536;

  const int n4 = N * 128 / 4;
  const int cb = (n4 + 255) / 256;           // convert blocks
  const int wb = (3 * 32768) / 256;          // weight blocks (384)
  const int HB = (N + 255) / 256;            // high-byte buckets (196)
  const int SN = 256 * RNB;                  // scan length 32768
  const int snb = SN / 1024;                 // 32 scan blocks

  // prep (convert + fp8 + weights + radix hist)
  prep_kernel<<<cb + wb + RNB, 256, 0, stream>>>(x, xh, xh8, n4, ei, ghist, E,
                                                 W1l, W1r, W2l, W2r, Wlin, wt, cb, wb);
  // CSR build (atomic-free; chunk prefixes folded into consumers)
  scan_block_kernel<<<snb, 1024, 0, stream>>>(ghist, sg, sums, SN);
  radix_scatter<<<RNB, 256, 0, stream>>>(ei, sg, sums, tmp, E);
  radix_bucket<<<HB, 256, 0, stream>>>(tmp, sg, sums, srcs, off, N, E, HB);

  const int aggBlocks  = ((N + 1) / 2 + 3) / 4;   // 2 nodes/wave, 4 waves/block
  const int gemmBlocks = (N + 127) / 128;         // 128 rows/block
  const int c8Blocks   = (N * 128 / 8 + 255) / 256;

  // layer 1: x1 = relu(mean(x) @ W1_l + x @ W1_r + b1)
  aggregate8_kernel<<<aggBlocks, 256, 0, stream>>>((const uint4*)xh8, off, srcs, mh, N);
  gemm_kernel<true, true><<<gemmBlocks, 256, 0, stream>>>(mh, xh, wt1, b1l, x1h, N);
  conv8_kernel<<<c8Blocks, 256, 0, stream>>>(x1h, x1h8, N * 128 / 8);
  // layer 2: x2 = relu(mean(x1) @ W2_l + x1 @ W2_r + b2)
  aggregate8_kernel<<<aggBlocks, 256, 0, stream>>>((const uint4*)x1h8, off, srcs, mh, N);
  gemm_kernel<true, true><<<gemmBlocks, 256, 0, stream>>>(mh, x1h, wt2, b2l, x2h, N);
  // head: out = [x1|x2] @ W_lin + b_lin   (fp32 out)
  gemm_kernel<false, false><<<gemmBlocks, 256, 0, stream>>>(x1h, x2h, wt3, blin, d_out, N);
}